// Round 4
// baseline (941.573 us; speedup 1.0000x reference)
//
#include <hip/hip_runtime.h>
#include <math.h>

#define Tdim 2048
#define HIDd 1024
#define NHd 16
#define NCOL 4096         // NH*16*16
#define Cn 64             // chunks per sequence
#define Ln 32             // chunk length (Cn*Ln == Tdim)
#define LSTR 40           // f16 elems per LDS row (80 B): bank-friendly pad (gemm2)
#define KCAT 3072         // concatenated K: [Ah|Ah/32|Al*32] x [Bh|Bl*32|Bh/32]
#define KB 6144           // KCAT * sizeof(_Float16)

typedef _Float16 f16x4  __attribute__((ext_vector_type(4)));
typedef _Float16 f16x8  __attribute__((ext_vector_type(8)));
typedef float    f32x4  __attribute__((ext_vector_type(4)));

typedef __attribute__((address_space(1))) void gvoid_t;
typedef __attribute__((address_space(3))) void lvoid_t;

// ---------------- hs (rows x 1024 fp32) -> A_cat (rows x 3072 f16) ------------------------
__global__ __launch_bounds__(256) void conv_A_kernel(const float* __restrict__ hs,
                                                     _Float16* __restrict__ Ac)
{
    const size_t i = ((size_t)blockIdx.x * 256 + threadIdx.x) * 8;
    const size_t r = i >> 10, k = i & 1023;
    const float4 x0 = *(const float4*)(hs + i);
    const float4 x1 = *(const float4*)(hs + i + 4);
    const float v[8] = {x0.x, x0.y, x0.z, x0.w, x1.x, x1.y, x1.z, x1.w};
    f16x8 h, hm, l;
#pragma unroll
    for (int j = 0; j < 8; ++j) {
        const _Float16 hh = (_Float16)v[j];
        h[j]  = hh;
        hm[j] = (_Float16)(v[j] * 0.03125f);          // == hh/32 exactly (pow2 scale)
        l[j]  = (_Float16)((v[j] - (float)hh) * 32.0f);
    }
    _Float16* o = Ac + r * KCAT + k;
    *(f16x8*)(o)        = h;
    *(f16x8*)(o + 1024) = hm;
    *(f16x8*)(o + 2048) = l;
}

// ---------------- W_mat (1024 x 4096 fp32) -> B_cat (4096 x 3072 f16) ---------------------
__global__ __launch_bounds__(256) void conv_B_kernel(const float* __restrict__ W,
                                                     _Float16* __restrict__ Bc)
{
    __shared__ float t[32][33];
    const int tx = threadIdx.x & 31, ty = threadIdx.x >> 5;   // ty 0..7
    const int n0 = blockIdx.x * 32, k0 = blockIdx.y * 32;
#pragma unroll
    for (int i = 0; i < 4; ++i)
        t[ty + i * 8][tx] = W[(size_t)(k0 + ty + i * 8) * NCOL + n0 + tx];
    __syncthreads();
#pragma unroll
    for (int i = 0; i < 4; ++i) {
        const float w = t[tx][ty + i * 8];
        const _Float16 h = (_Float16)w;
        const size_t o = (size_t)(n0 + ty + i * 8) * KCAT + k0 + tx;
        Bc[o]        = h;
        Bc[o + 1024] = (_Float16)((w - (float)h) * 32.0f);
        Bc[o + 2048] = (_Float16)((float)h * 0.03125f);   // exact
    }
}

// ---------------- W_out (512 x 1024 fp32) -> W2T (1024 x 512 fp16) ------------------------
__global__ __launch_bounds__(256) void conv_W2T_kernel(const float* __restrict__ W,
                                                       _Float16* __restrict__ WT)
{
    __shared__ float t[32][33];
    const int tx = threadIdx.x & 31, ty = threadIdx.x >> 5;
    const int n0 = blockIdx.x * 32, k0 = blockIdx.y * 32;
#pragma unroll
    for (int i = 0; i < 4; ++i)
        t[ty + i * 8][tx] = W[(size_t)(k0 + ty + i * 8) * 1024 + n0 + tx];
    __syncthreads();
#pragma unroll
    for (int i = 0; i < 4; ++i)
        WT[(size_t)(n0 + ty + i * 8) * 512 + k0 + tx] = (_Float16)t[tx][ty + i * 8];
}

// ---------------- GEMM1: 256x256 tile, BK=64, 8-phase counted-vmcnt pipeline --------------
#define MFMA_PHASE(CPH) \
    _Pragma("unroll") \
    for (int m2_ = 0; m2_ < 2; ++m2_) { \
        _Pragma("unroll") \
        for (int nt_ = 0; nt_ < 4; ++nt_) { \
            acc[(CPH)*2 + m2_][nt_] = __builtin_amdgcn_mfma_f32_16x16x32_f16(af[m2_][0], bf[nt_][0], acc[(CPH)*2 + m2_][nt_], 0, 0, 0); \
            acc[(CPH)*2 + m2_][nt_] = __builtin_amdgcn_mfma_f32_16x16x32_f16(af[m2_][1], bf[nt_][1], acc[(CPH)*2 + m2_][nt_], 0, 0, 0); \
        } \
    }

#define PHASE(BUF, CPH, STAGE_EXPR, DOGATE) do { \
    af[0][0] = readA(BUF, (CPH)*2,     0); \
    af[0][1] = readA(BUF, (CPH)*2,     1); \
    af[1][0] = readA(BUF, (CPH)*2 + 1, 0); \
    af[1][1] = readA(BUF, (CPH)*2 + 1, 1); \
    if ((CPH) == 0) { \
        _Pragma("unroll") \
        for (int nt_ = 0; nt_ < 4; ++nt_) { bf[nt_][0] = readB(BUF, nt_, 0); bf[nt_][1] = readB(BUF, nt_, 1); } \
    } \
    STAGE_EXPR; \
    asm volatile("s_barrier" ::: "memory"); \
    asm volatile("s_waitcnt lgkmcnt(0)" ::: "memory"); \
    __builtin_amdgcn_sched_barrier(0); \
    __builtin_amdgcn_s_setprio(1); \
    MFMA_PHASE(CPH) \
    __builtin_amdgcn_s_setprio(0); \
    if (DOGATE) { \
        if (notlast) asm volatile("s_waitcnt vmcnt(6)" ::: "memory"); \
        else         asm volatile("s_waitcnt vmcnt(0)" ::: "memory"); \
    } \
    asm volatile("s_barrier" ::: "memory"); \
} while (0)

__global__ __launch_bounds__(512, 2) void gemm1_8ph(const _Float16* __restrict__ A,
                                                    const _Float16* __restrict__ B,
                                                    const float* __restrict__ bias,
                                                    float* __restrict__ Mout)
{
    __shared__ __align__(16) _Float16 sA[2][256 * 64];
    __shared__ __align__(16) _Float16 sB[2][256 * 64];
    const int tid = threadIdx.x;
    const int lane = tid & 63;
    const int wid = tid >> 6;
    const int wm = wid >> 2, wn = wid & 3;        // wave grid 2 (M) x 4 (N)
    const int q = lane >> 4, ln = lane & 15;
    const int col0 = blockIdx.x * 256;
    const int row0 = blockIdx.y * 256;

    const char* Ab = (const char*)A + (size_t)row0 * KB;
    const char* Bb = (const char*)B + (size_t)col0 * KB;

    auto stage_chunk = [&](const char* g, int fr, int kt, char* ldsbase) {
        const int rr = tid >> 3;
        const int cb = (tid & 7) << 4;
        const char* src = g + (size_t)(fr + rr) * KB + (size_t)kt * 128 + (cb ^ ((rr & 7) << 4));
        char* dst = ldsbase + ((tid >> 6) << 10);
        __builtin_amdgcn_global_load_lds((gvoid_t*)src, (lvoid_t*)dst, 16, 0, 0);
    };
    auto stageA2 = [&](int b, int t, int h) {
        stage_chunk(Ab, h * 64,       t, (char*)&sA[b][0] + (size_t)(h * 64) * 128);
        stage_chunk(Ab, 128 + h * 64, t, (char*)&sA[b][0] + (size_t)(128 + h * 64) * 128);
    };
    auto stageB2 = [&](int b, int t, int h) {
        stage_chunk(Bb, h * 128,      t, (char*)&sB[b][0] + (size_t)(h * 128) * 128);
        stage_chunk(Bb, h * 128 + 64, t, (char*)&sB[b][0] + (size_t)(h * 128 + 64) * 128);
    };
    auto readA = [&](int b, int mf, int ks) -> f16x8 {
        const int r = wm * 128 + mf * 16 + ln;
        return *(const f16x8*)((const char*)&sA[b][0] + r * 128 + ((ks * 64 + q * 16) ^ ((r & 7) << 4)));
    };
    auto readB = [&](int b, int nt, int ks) -> f16x8 {
        const int r = wn * 64 + nt * 16 + ln;
        return *(const f16x8*)((const char*)&sB[b][0] + r * 128 + ((ks * 64 + q * 16) ^ ((r & 7) << 4)));
    };

    stageB2(0, 0, 0); stageB2(0, 0, 1); stageA2(0, 0, 0); stageA2(0, 0, 1);
    stageB2(1, 1, 0); stageB2(1, 1, 1); stageA2(1, 1, 0);

    f32x4 acc[8][4];
    const f32x4 z4 = {0.f, 0.f, 0.f, 0.f};
#pragma unroll
    for (int mf = 0; mf < 8; ++mf)
#pragma unroll
        for (int nt = 0; nt < 4; ++nt) acc[mf][nt] = z4;

    asm volatile("s_waitcnt vmcnt(6)" ::: "memory");
    asm volatile("s_barrier" ::: "memory");

    f16x8 af[2][2];
    f16x8 bf[4][2];

#pragma unroll 1
    for (int it = 0; it < 24; ++it) {
        const int t0 = it * 2;
        const bool notlast = (it != 23);
        PHASE(0, 0, (stageA2(1, t0 + 1, 1)), 0);
        PHASE(0, 1, (notlast ? stageB2(0, t0 + 2, 0) : (void)0), 0);
        PHASE(0, 2, (notlast ? stageB2(0, t0 + 2, 1) : (void)0), 0);
        PHASE(0, 3, (notlast ? stageA2(0, t0 + 2, 0) : (void)0), 1);
        PHASE(1, 0, (notlast ? stageA2(0, t0 + 2, 1) : (void)0), 0);
        PHASE(1, 1, (notlast ? stageB2(1, t0 + 3, 0) : (void)0), 0);
        PHASE(1, 2, (notlast ? stageB2(1, t0 + 3, 1) : (void)0), 0);
        PHASE(1, 3, (notlast ? stageA2(1, t0 + 3, 0) : (void)0), 1);
    }

#pragma unroll
    for (int nt = 0; nt < 4; ++nt) {
        const int c = col0 + wn * 64 + nt * 16 + ln;
        const float bv = bias[c];
        const int h = c >> 8, e = c & 255;
#pragma unroll
        for (int mf = 0; mf < 8; ++mf) {
#pragma unroll
            for (int r = 0; r < 4; ++r) {
                const int row = row0 + wm * 128 + mf * 16 + q * 4 + r;
                const int bbl = row >> 11, t = row & 2047;
                Mout[((size_t)(bbl * 16 + h) * Tdim + t) * 256 + e] = acc[mf][nt][r] + bv;
            }
        }
    }
}

// ---------------- Stage A2: per-direction prefix-product chains, one wave per (seq,c,dir) --
// Wave 0 (lr): ascending t, prefix P_s = M^_{t0+s}···M^_{t0}.  Wave 1 (rl): descending t,
// prefix R_s = M^_{t1-s}···M^_{t1}.  Both are plain left-multiplies (row fragments only).
// Each prefix is stored to P (f16, row-major 16x16) for the parallel replay in stageC2.
// Rescale (arbitrary positive scalar) every 2nd step only: 2 unrescaled steps bound
// |v| <= ~3100 << f16 max, and the hi/lo split keeps ~21 bits at any scale.
__global__ __launch_bounds__(128) void stageA2_mfma(const float* __restrict__ m,
                                                    float* __restrict__ q,
                                                    _Float16* __restrict__ P, int SS)
{
    const int tid = threadIdx.x;
    const int dir = tid >> 6;                 // wave 0 = lr, wave 1 = rl
    const int lane = tid & 63;
    const int qd = lane >> 4, ln = lane & 15;
    const int sc = blockIdx.x;
    const int seq = sc >> 6, c = sc & (Cn - 1);
    const float* mp = m + ((size_t)seq * Tdim + c * Ln) * 256;
    _Float16* Pp = P + (((size_t)(dir * SS + seq) * Cn + c) * Ln) * 256
                     + (qd * 4) * 16 + ln;

    float v[4];                               // running product, B/D fragment layout
#pragma unroll
    for (int r = 0; r < 4; ++r) v[r] = (qd * 4 + r == ln) ? 1.0f : 0.0f;

    const int dstep = dir ? -256 : 256;
    const float* Ms = mp + (dir ? (Ln - 1) * 256 : 0) + ln * 16 + qd * 4;

    // prologue: prefetch M_0 row fragment + its Frobenius scale
    float4 arow = *(const float4*)Ms;
    float f2 = arow.x*arow.x + arow.y*arow.y + arow.z*arow.z + arow.w*arow.w;
#pragma unroll
    for (int off = 1; off < 64; off <<= 1) f2 += __shfl_xor(f2, off);
    float sm = 4.0f * rsqrtf(f2 + 1e-12f);

    for (int s = 0; s < Ln; ++s) {
        // split sm-scaled M row fragment (hi + lo*1024)
        f16x4 mh, mlo;
        const float ar[4] = {arow.x * sm, arow.y * sm, arow.z * sm, arow.w * sm};
#pragma unroll
        for (int i = 0; i < 4; ++i) {
            const _Float16 h = (_Float16)ar[i];
            mh[i] = h; mlo[i] = (_Float16)((ar[i] - (float)h) * 1024.0f);
        }
        // prefetch next M; its f2/sm chain overlaps this step's MFMA chain
        float smn = sm;
        if (s + 1 < Ln) {
            Ms += dstep;
            arow = *(const float4*)Ms;
            float f2n = arow.x*arow.x + arow.y*arow.y + arow.z*arow.z + arow.w*arow.w;
#pragma unroll
            for (int off = 1; off < 64; off <<= 1) f2n += __shfl_xor(f2n, off);
            smn = 4.0f * rsqrtf(f2n + 1e-12f);
        }
        // split running product (hi + lo*1024)
        f16x4 qh, ql;
#pragma unroll
        for (int r = 0; r < 4; ++r) {
            const _Float16 h = (_Float16)v[r];
            qh[r] = h; ql[r] = (_Float16)((v[r] - (float)h) * 1024.0f);
        }
        f32x4 a1 = {0.f,0.f,0.f,0.f}, a2 = {0.f,0.f,0.f,0.f};
        a1 = __builtin_amdgcn_mfma_f32_16x16x16f16(mh,  qh, a1, 0, 0, 0);
        a2 = __builtin_amdgcn_mfma_f32_16x16x16f16(mh,  ql, a2, 0, 0, 0);
        a2 = __builtin_amdgcn_mfma_f32_16x16x16f16(mlo, qh, a2, 0, 0, 0);
#pragma unroll
        for (int r = 0; r < 4; ++r) v[r] = a1[r] + a2[r] * (1.0f / 1024.0f);

        if (s & 1) {                          // rescale every 2nd step (value arbitrary)
            float mx = 0.f;
#pragma unroll
            for (int r = 0; r < 4; ++r) mx = fmaxf(mx, fabsf(v[r]));
#pragma unroll
            for (int off = 1; off < 64; off <<= 1) mx = fmaxf(mx, __shfl_xor(mx, off));
            const float inv = 1.0f / (mx + 1e-30f);
#pragma unroll
            for (int r = 0; r < 4; ++r) v[r] *= inv;
        }
        // store prefix P_s (f16 row-major; stageC2 normalizes, so scale is arbitrary)
#pragma unroll
        for (int r = 0; r < 4; ++r)
            Pp[(size_t)s * 256 + r * 16] = (_Float16)v[r];
        sm = smn;
    }

    // final L2 normalize + store chunk map for stageB (row-major)
    float ss = 0.f;
#pragma unroll
    for (int r = 0; r < 4; ++r) ss += v[r] * v[r];
#pragma unroll
    for (int off = 1; off < 64; off <<= 1) ss += __shfl_xor(ss, off);
    const float sl = 1.0f / (sqrtf(ss) + 1e-30f);
    float* qo = q + ((size_t)(dir * SS + seq) * Cn + c) * 256;
#pragma unroll
    for (int r = 0; r < 4; ++r)
        qo[(qd * 4 + r) * 16 + ln] = v[r] * sl;
}

// ---------------- Stage B: cross-chunk vector propagation (unchanged, r3-proven) ----------
__global__ __launch_bounds__(64) void stageB_kernel(const float* __restrict__ q,
                                                    float* __restrict__ vs, int SS)
{
    const int lane = threadIdx.x & 63;
    const int i = lane & 15;
    const int chain = blockIdx.x;
    const int dir = (chain >= SS) ? 1 : 0;
    const int seq = chain - dir * SS;
    const float* qb = q + (size_t)(dir * SS + seq) * Cn * 256;
    float* vb = vs + (size_t)(dir * SS + seq) * Cn * 16;

    float myw = (i == 0) ? 1.0f : 0.0f;
    float wv[16];
#pragma unroll
    for (int k2 = 0; k2 < 16; ++k2) wv[k2] = (k2 == 0) ? 1.0f : 0.0f;

    int cc = dir ? (Cn - 1) : 0;
    const float* Qp = qb + (size_t)cc * 256 + i * 16;
    float4 q0 = *(const float4*)(Qp + 0);
    float4 q1 = *(const float4*)(Qp + 4);
    float4 q2 = *(const float4*)(Qp + 8);
    float4 q3 = *(const float4*)(Qp + 12);

    for (int s = 0; s < Cn; ++s) {
        vb[cc * 16 + i] = myw;
        float nv = q0.x*wv[0] + q0.y*wv[1] + q0.z*wv[2] + q0.w*wv[3]
                 + q1.x*wv[4] + q1.y*wv[5] + q1.z*wv[6] + q1.w*wv[7]
                 + q2.x*wv[8] + q2.y*wv[9] + q2.z*wv[10] + q2.w*wv[11]
                 + q3.x*wv[12] + q3.y*wv[13] + q3.z*wv[14] + q3.w*wv[15];
        if (s + 1 < Cn) {                       // prefetch next chunk's Q
            const int ccn = dir ? (Cn - 2 - s) : (s + 1);
            const float* Qn = qb + (size_t)ccn * 256 + i * 16;
            q0 = *(const float4*)(Qn + 0);
            q1 = *(const float4*)(Qn + 4);
            q2 = *(const float4*)(Qn + 8);
            q3 = *(const float4*)(Qn + 12);
        }
        float s2 = nv * nv;
        s2 += __shfl_xor(s2, 1); s2 += __shfl_xor(s2, 2);
        s2 += __shfl_xor(s2, 4); s2 += __shfl_xor(s2, 8);
        const float wn = nv / (sqrtf(s2) + 1e-20f);
        myw = wn;
#pragma unroll
        for (int k2 = 0; k2 < 16; ++k2) wv[k2] = __shfl(wn, (lane & 48) | k2);
        cc = dir ? (Cn - 2 - s) : (s + 1);
    }
}

// ---------------- Stage C2: parallel replay x_t = normalize(P_s . v_start) ---------------
// One wave per (dir,seq,c). No serial chain: the 8 t-groups are independent (full ILP),
// P reads are f16 and perfectly coalesced (wave covers 2 KB contiguous per group).
__global__ __launch_bounds__(256) void stageC2_kernel(const _Float16* __restrict__ P,
                                                      const float* __restrict__ vs,
                                                      _Float16* __restrict__ x, int SS)
{
    const int tid = threadIdx.x;
    const int wave = tid >> 6, lane = tid & 63;
    const int dsc = blockIdx.x * 4 + wave;        // (dir*SS + seq)*Cn + c
    const int dirseq = dsc >> 6, c = dsc & (Cn - 1);
    const int dir = (dirseq >= SS) ? 1 : 0;
    const int seq = dirseq - dir * SS;
    const int bbl = seq >> 4, h = seq & 15;
    const _Float16* Pp = P + (size_t)dsc * (Ln * 256);
    const float* vp = vs + (size_t)dsc * 16;

    float v[16];
#pragma unroll
    for (int k = 0; k < 16; ++k) v[k] = vp[k];    // wave-uniform -> broadcast loads

    const int tt = lane >> 4, j = lane & 15;
    const int t0 = c * Ln;
#pragma unroll
    for (int g = 0; g < 8; ++g) {
        const int s = g * 4 + tt;
        const _Float16* pr = Pp + (size_t)s * 256 + j * 16;
        const f16x8 p0 = *(const f16x8*)(pr);
        const f16x8 p1 = *(const f16x8*)(pr + 8);
        float nv = 0.f;
#pragma unroll
        for (int k = 0; k < 8; ++k) nv += (float)p0[k] * v[k];
#pragma unroll
        for (int k = 0; k < 8; ++k) nv += (float)p1[k] * v[k + 8];
        float s2 = nv * nv;
        s2 += __shfl_xor(s2, 1); s2 += __shfl_xor(s2, 2);
        s2 += __shfl_xor(s2, 4); s2 += __shfl_xor(s2, 8);
        const float vn = nv / (sqrtf(s2) + 1e-6f);   // reference VEC_EPS semantics
        const int t = dir ? (t0 + Ln - 1 - s) : (t0 + s);
        x[(((size_t)bbl * Tdim + t) * NHd + h) * 32 + dir * 16 + j] = (_Float16)vn;
    }
}

// ---------------- GEMM2 (f16 MFMA): out = gelu(x @ W_out + b_out) -------------------------
__global__ __launch_bounds__(256) void gemm2_f16(const _Float16* __restrict__ A,
                                                 const _Float16* __restrict__ BT,
                                                 const float* __restrict__ bias,
                                                 float* __restrict__ out, int row0)
{
    __shared__ _Float16 Al[128 * LSTR];
    __shared__ _Float16 Bl[128 * LSTR];
    const int tid = threadIdx.x;
    const int wave = tid >> 6, lane = tid & 63;
    const int wm = wave & 1, wn = wave >> 1;
    const int qd = lane >> 4, ln = lane & 15;
    const int r0 = blockIdx.y * 128;
    const int c0 = blockIdx.x * 128;

    f32x4 acc[4][4] = {{{0.f,0.f,0.f,0.f}}};

    const int sr = tid >> 2, sc = tid & 3;
    const _Float16* Ag = A  + (size_t)(r0 + sr) * 512 + sc * 8;
    const _Float16* Bg = BT + (size_t)(c0 + sr) * 512 + sc * 8;
    _Float16* Alw = &Al[sr * LSTR + sc * 8];
    _Float16* Blw = &Bl[sr * LSTR + sc * 8];

    for (int k0 = 0; k0 < 512; k0 += 32) {
        const f16x8 a0 = *(const f16x8*)(Ag + k0);
        const f16x8 a1 = *(const f16x8*)(Ag + (size_t)64 * 512 + k0);
        const f16x8 b0 = *(const f16x8*)(Bg + k0);
        const f16x8 b1 = *(const f16x8*)(Bg + (size_t)64 * 512 + k0);
        __syncthreads();
        *(f16x8*)(Alw)             = a0;
        *(f16x8*)(Alw + 64 * LSTR) = a1;
        *(f16x8*)(Blw)             = b0;
        *(f16x8*)(Blw + 64 * LSTR) = b1;
        __syncthreads();
        f16x8 af[4], bfr[4];
#pragma unroll
        for (int mt = 0; mt < 4; ++mt)
            af[mt] = *(const f16x8*)&Al[(wm * 64 + mt * 16 + ln) * LSTR + qd * 8];
#pragma unroll
        for (int nt = 0; nt < 4; ++nt)
            bfr[nt] = *(const f16x8*)&Bl[(wn * 64 + nt * 16 + ln) * LSTR + qd * 8];
#pragma unroll
        for (int mt = 0; mt < 4; ++mt)
#pragma unroll
            for (int nt = 0; nt < 4; ++nt)
                acc[mt][nt] = __builtin_amdgcn_mfma_f32_16x16x32_f16(af[mt], bfr[nt], acc[mt][nt], 0, 0, 0);
    }
#pragma unroll
    for (int nt = 0; nt < 4; ++nt) {
        const int c = c0 + wn * 64 + nt * 16 + ln;
        const float bv = bias[c];
#pragma unroll
        for (int mt = 0; mt < 4; ++mt) {
#pragma unroll
            for (int r = 0; r < 4; ++r) {
                const int row = r0 + wm * 64 + mt * 16 + qd * 4 + r;
                float v = acc[mt][nt][r] + bv;
                v = 0.5f * v * (1.0f + erff(v * 0.70710678118654752f));
                out[(size_t)(row0 + row) * 1024 + c] = v;
            }
        }
    }
}

extern "C" void kernel_launch(void* const* d_in, const int* in_sizes, int n_in,
                              void* d_out, int out_size, void* d_ws, size_t ws_size,
                              hipStream_t stream)
{
    const float* hs    = (const float*)d_in[0];
    const float* W_mat = (const float*)d_in[1];
    const float* b_mat = (const float*)d_in[2];
    const float* W_out = (const float*)d_in[3];
    const float* b_out = (const float*)d_in[4];
    float* out = (float*)d_out;

    // layout: W2T(1M) Bcat(24M) | per bb-group: m 32M | qx 2M (q f32 / x f16 aliased) |
    //         Acat 12M | P 32M (f16 prefix products) | vs 128K
    const size_t per_bb = (32ull << 20) + (2ull << 20) + (12ull << 20) + (32ull << 20)
                        + (128ull << 10);
    const size_t wbase  = 25ull << 20;
    int nbb = 8;
    while (nbb > 1 && ws_size < wbase + (size_t)nbb * per_bb) nbb >>= 1;

    char* base = (char*)d_ws;
    _Float16* W2T = (_Float16*)base;
    _Float16* Bc  = (_Float16*)(base + (1ull << 20));
    size_t off = wbase;
    float* m  = (float*)(base + off);  off += (size_t)nbb * (32ull << 20);
    float* qx = (float*)(base + off);  off += (size_t)nbb * (2ull << 20);
    _Float16* Ac = (_Float16*)(base + off); off += (size_t)nbb * (12ull << 20);
    _Float16* P  = (_Float16*)(base + off); off += (size_t)nbb * (32ull << 20);
    float* vs = (float*)(base + off);

    conv_B_kernel<<<dim3(128, 32), 256, 0, stream>>>(W_mat, Bc);
    conv_W2T_kernel<<<dim3(32, 16), 256, 0, stream>>>(W_out, W2T);

    for (int bb0 = 0; bb0 < 8; bb0 += nbb) {
        const int row0 = bb0 * Tdim;
        const int SS = nbb * 16;
        conv_A_kernel<<<nbb * 1024, 256, 0, stream>>>(hs + (size_t)row0 * HIDd, Ac);
        gemm1_8ph<<<dim3(16, nbb * 8), 512, 0, stream>>>(Ac, Bc, b_mat, m);
        stageA2_mfma<<<SS * 64, 128, 0, stream>>>(m, qx, P, SS);
        stageB_kernel<<<2 * SS, 64, 0, stream>>>(qx, vs, SS);
        stageC2_kernel<<<SS * 32, 256, 0, stream>>>(P, vs, (_Float16*)qx, SS);
        gemm2_f16<<<dim3(8, nbb * 16), 256, 0, stream>>>((_Float16*)qx, W2T, b_out, out, row0);
    }
}

// Round 5
// 877.927 us; speedup vs baseline: 1.0725x; 1.0725x over previous
//
#include <hip/hip_runtime.h>
#include <math.h>

#define Tdim 2048
#define HIDd 1024
#define NHd 16
#define NCOL 4096         // NH*16*16
#define Cn 64             // chunks per sequence
#define Ln 32             // chunk length (Cn*Ln == Tdim)
#define LSTR 40           // f16 elems per LDS row (80 B): bank-friendly pad (gemm2)
#define KCAT 3072         // concatenated K: [Ah|Ah/32|Al*32] x [Bh|Bl*32|Bh/32]
#define KB 6144           // KCAT * sizeof(_Float16)

typedef _Float16 f16x4  __attribute__((ext_vector_type(4)));
typedef _Float16 f16x8  __attribute__((ext_vector_type(8)));
typedef float    f32x4  __attribute__((ext_vector_type(4)));

typedef __attribute__((address_space(1))) void gvoid_t;
typedef __attribute__((address_space(3))) void lvoid_t;

// ---------------- hs (rows x 1024 fp32) -> A_cat (rows x 3072 f16) ------------------------
__global__ __launch_bounds__(256) void conv_A_kernel(const float* __restrict__ hs,
                                                     _Float16* __restrict__ Ac)
{
    const size_t i = ((size_t)blockIdx.x * 256 + threadIdx.x) * 8;
    const size_t r = i >> 10, k = i & 1023;
    const float4 x0 = *(const float4*)(hs + i);
    const float4 x1 = *(const float4*)(hs + i + 4);
    const float v[8] = {x0.x, x0.y, x0.z, x0.w, x1.x, x1.y, x1.z, x1.w};
    f16x8 h, hm, l;
#pragma unroll
    for (int j = 0; j < 8; ++j) {
        const _Float16 hh = (_Float16)v[j];
        h[j]  = hh;
        hm[j] = (_Float16)(v[j] * 0.03125f);          // == hh/32 exactly (pow2 scale)
        l[j]  = (_Float16)((v[j] - (float)hh) * 32.0f);
    }
    _Float16* o = Ac + r * KCAT + k;
    *(f16x8*)(o)        = h;
    *(f16x8*)(o + 1024) = hm;
    *(f16x8*)(o + 2048) = l;
}

// ---------------- W_mat (1024 x 4096 fp32) -> B_cat (4096 x 3072 f16) ---------------------
__global__ __launch_bounds__(256) void conv_B_kernel(const float* __restrict__ W,
                                                     _Float16* __restrict__ Bc)
{
    __shared__ float t[32][33];
    const int tx = threadIdx.x & 31, ty = threadIdx.x >> 5;   // ty 0..7
    const int n0 = blockIdx.x * 32, k0 = blockIdx.y * 32;
#pragma unroll
    for (int i = 0; i < 4; ++i)
        t[ty + i * 8][tx] = W[(size_t)(k0 + ty + i * 8) * NCOL + n0 + tx];
    __syncthreads();
#pragma unroll
    for (int i = 0; i < 4; ++i) {
        const float w = t[tx][ty + i * 8];
        const _Float16 h = (_Float16)w;
        const size_t o = (size_t)(n0 + ty + i * 8) * KCAT + k0 + tx;
        Bc[o]        = h;
        Bc[o + 1024] = (_Float16)((w - (float)h) * 32.0f);
        Bc[o + 2048] = (_Float16)((float)h * 0.03125f);   // exact
    }
}

// ---------------- W_out (512 x 1024 fp32) -> W2T (1024 x 512 fp16) ------------------------
__global__ __launch_bounds__(256) void conv_W2T_kernel(const float* __restrict__ W,
                                                       _Float16* __restrict__ WT)
{
    __shared__ float t[32][33];
    const int tx = threadIdx.x & 31, ty = threadIdx.x >> 5;
    const int n0 = blockIdx.x * 32, k0 = blockIdx.y * 32;
#pragma unroll
    for (int i = 0; i < 4; ++i)
        t[ty + i * 8][tx] = W[(size_t)(k0 + ty + i * 8) * 1024 + n0 + tx];
    __syncthreads();
#pragma unroll
    for (int i = 0; i < 4; ++i)
        WT[(size_t)(n0 + ty + i * 8) * 512 + k0 + tx] = (_Float16)t[tx][ty + i * 8];
}

// ---------------- GEMM1: 256x256 tile, BK=64, 8-phase counted-vmcnt pipeline --------------
#define MFMA_PHASE(CPH) \
    _Pragma("unroll") \
    for (int m2_ = 0; m2_ < 2; ++m2_) { \
        _Pragma("unroll") \
        for (int nt_ = 0; nt_ < 4; ++nt_) { \
            acc[(CPH)*2 + m2_][nt_] = __builtin_amdgcn_mfma_f32_16x16x32_f16(af[m2_][0], bf[nt_][0], acc[(CPH)*2 + m2_][nt_], 0, 0, 0); \
            acc[(CPH)*2 + m2_][nt_] = __builtin_amdgcn_mfma_f32_16x16x32_f16(af[m2_][1], bf[nt_][1], acc[(CPH)*2 + m2_][nt_], 0, 0, 0); \
        } \
    }

#define PHASE(BUF, CPH, STAGE_EXPR, DOGATE) do { \
    af[0][0] = readA(BUF, (CPH)*2,     0); \
    af[0][1] = readA(BUF, (CPH)*2,     1); \
    af[1][0] = readA(BUF, (CPH)*2 + 1, 0); \
    af[1][1] = readA(BUF, (CPH)*2 + 1, 1); \
    if ((CPH) == 0) { \
        _Pragma("unroll") \
        for (int nt_ = 0; nt_ < 4; ++nt_) { bf[nt_][0] = readB(BUF, nt_, 0); bf[nt_][1] = readB(BUF, nt_, 1); } \
    } \
    STAGE_EXPR; \
    asm volatile("s_barrier" ::: "memory"); \
    asm volatile("s_waitcnt lgkmcnt(0)" ::: "memory"); \
    __builtin_amdgcn_sched_barrier(0); \
    __builtin_amdgcn_s_setprio(1); \
    MFMA_PHASE(CPH) \
    __builtin_amdgcn_s_setprio(0); \
    if (DOGATE) { \
        if (notlast) asm volatile("s_waitcnt vmcnt(6)" ::: "memory"); \
        else         asm volatile("s_waitcnt vmcnt(0)" ::: "memory"); \
    } \
    asm volatile("s_barrier" ::: "memory"); \
} while (0)

__global__ __launch_bounds__(512, 2) void gemm1_8ph(const _Float16* __restrict__ A,
                                                    const _Float16* __restrict__ B,
                                                    const float* __restrict__ bias,
                                                    float* __restrict__ Mout)
{
    __shared__ __align__(16) _Float16 sA[2][256 * 64];
    __shared__ __align__(16) _Float16 sB[2][256 * 64];
    const int tid = threadIdx.x;
    const int lane = tid & 63;
    const int wid = tid >> 6;
    const int wm = wid >> 2, wn = wid & 3;        // wave grid 2 (M) x 4 (N)
    const int q = lane >> 4, ln = lane & 15;
    const int col0 = blockIdx.x * 256;
    const int row0 = blockIdx.y * 256;

    const char* Ab = (const char*)A + (size_t)row0 * KB;
    const char* Bb = (const char*)B + (size_t)col0 * KB;

    auto stage_chunk = [&](const char* g, int fr, int kt, char* ldsbase) {
        const int rr = tid >> 3;
        const int cb = (tid & 7) << 4;
        const char* src = g + (size_t)(fr + rr) * KB + (size_t)kt * 128 + (cb ^ ((rr & 7) << 4));
        char* dst = ldsbase + ((tid >> 6) << 10);
        __builtin_amdgcn_global_load_lds((gvoid_t*)src, (lvoid_t*)dst, 16, 0, 0);
    };
    auto stageA2g = [&](int b, int t, int h) {
        stage_chunk(Ab, h * 64,       t, (char*)&sA[b][0] + (size_t)(h * 64) * 128);
        stage_chunk(Ab, 128 + h * 64, t, (char*)&sA[b][0] + (size_t)(128 + h * 64) * 128);
    };
    auto stageB2 = [&](int b, int t, int h) {
        stage_chunk(Bb, h * 128,      t, (char*)&sB[b][0] + (size_t)(h * 128) * 128);
        stage_chunk(Bb, h * 128 + 64, t, (char*)&sB[b][0] + (size_t)(h * 128 + 64) * 128);
    };
    auto readA = [&](int b, int mf, int ks) -> f16x8 {
        const int r = wm * 128 + mf * 16 + ln;
        return *(const f16x8*)((const char*)&sA[b][0] + r * 128 + ((ks * 64 + q * 16) ^ ((r & 7) << 4)));
    };
    auto readB = [&](int b, int nt, int ks) -> f16x8 {
        const int r = wn * 64 + nt * 16 + ln;
        return *(const f16x8*)((const char*)&sB[b][0] + r * 128 + ((ks * 64 + q * 16) ^ ((r & 7) << 4)));
    };

    stageB2(0, 0, 0); stageB2(0, 0, 1); stageA2g(0, 0, 0); stageA2g(0, 0, 1);
    stageB2(1, 1, 0); stageB2(1, 1, 1); stageA2g(1, 1, 0);

    f32x4 acc[8][4];
    const f32x4 z4 = {0.f, 0.f, 0.f, 0.f};
#pragma unroll
    for (int mf = 0; mf < 8; ++mf)
#pragma unroll
        for (int nt = 0; nt < 4; ++nt) acc[mf][nt] = z4;

    asm volatile("s_waitcnt vmcnt(6)" ::: "memory");
    asm volatile("s_barrier" ::: "memory");

    f16x8 af[2][2];
    f16x8 bf[4][2];

#pragma unroll 1
    for (int it = 0; it < 24; ++it) {
        const int t0 = it * 2;
        const bool notlast = (it != 23);
        PHASE(0, 0, (stageA2g(1, t0 + 1, 1)), 0);
        PHASE(0, 1, (notlast ? stageB2(0, t0 + 2, 0) : (void)0), 0);
        PHASE(0, 2, (notlast ? stageB2(0, t0 + 2, 1) : (void)0), 0);
        PHASE(0, 3, (notlast ? stageA2g(0, t0 + 2, 0) : (void)0), 1);
        PHASE(1, 0, (notlast ? stageA2g(0, t0 + 2, 1) : (void)0), 0);
        PHASE(1, 1, (notlast ? stageB2(1, t0 + 3, 0) : (void)0), 0);
        PHASE(1, 2, (notlast ? stageB2(1, t0 + 3, 1) : (void)0), 0);
        PHASE(1, 3, (notlast ? stageA2g(1, t0 + 3, 0) : (void)0), 1);
    }

#pragma unroll
    for (int nt = 0; nt < 4; ++nt) {
        const int c = col0 + wn * 64 + nt * 16 + ln;
        const float bv = bias[c];
        const int h = c >> 8, e = c & 255;
#pragma unroll
        for (int mf = 0; mf < 8; ++mf) {
#pragma unroll
            for (int r = 0; r < 4; ++r) {
                const int row = row0 + wm * 128 + mf * 16 + q * 4 + r;
                const int bbl = row >> 11, t = row & 2047;
                Mout[((size_t)(bbl * 16 + h) * Tdim + t) * 256 + e] = acc[mf][nt][r] + bv;
            }
        }
    }
}

// ---------------- Stage A2: prefix-product chains; P aliased OVER m -----------------------
// Block = (seq,c): stage the 32 KB m chunk into LDS, barrier, then wave 0 (lr, ascending)
// and wave 1 (rl, descending) run 3-MFMA split chains from LDS, writing each prefix (f16,
// 16x16 row-major) back over the chunk's own m slots: slot t bytes [dir*512, dir*512+512).
// For BOTH directions the prefix needed for output t lands at slot t.
__global__ __launch_bounds__(128) void stageA2_mfma(float* __restrict__ m,
                                                    float* __restrict__ q, int SS)
{
    __shared__ float Ml[Ln * 256];            // 32 KB chunk stage
    const int tid = threadIdx.x;
    const int dir = tid >> 6;                 // wave 0 = lr, wave 1 = rl
    const int lane = tid & 63;
    const int qd = lane >> 4, ln = lane & 15;
    const int sc = blockIdx.x;
    const int seq = sc >> 6, c = sc & (Cn - 1);
    float* mp = m + ((size_t)seq * Tdim + c * Ln) * 256;

    {   // cooperative stage: 2048 float4s over 128 threads
        const float4* src = (const float4*)mp;
        float4* dst = (float4*)Ml;
#pragma unroll
        for (int i = 0; i < 16; ++i)
            dst[tid + i * 128] = src[tid + i * 128];
    }
    __syncthreads();

    float v[4];                               // running product, B/D fragment layout
#pragma unroll
    for (int r = 0; r < 4; ++r) v[r] = (qd * 4 + r == ln) ? 1.0f : 0.0f;

    const int s0 = dir ? (Ln - 1) : 0;
    const int ds = dir ? -1 : 1;

    // prologue: read M_0 row fragment + its Frobenius scale
    int t = s0;
    float4 arow = *(const float4*)&Ml[t * 256 + ln * 16 + qd * 4];
    float f2 = arow.x*arow.x + arow.y*arow.y + arow.z*arow.z + arow.w*arow.w;
#pragma unroll
    for (int off = 1; off < 64; off <<= 1) f2 += __shfl_xor(f2, off);
    float sm = 4.0f * rsqrtf(f2 + 1e-12f);

    for (int s = 0; s < Ln; ++s) {
        const int tcur = t;
        // split sm-scaled M row fragment (hi + lo*1024)
        f16x4 mh, mlo;
        const float ar[4] = {arow.x * sm, arow.y * sm, arow.z * sm, arow.w * sm};
#pragma unroll
        for (int i = 0; i < 4; ++i) {
            const _Float16 h = (_Float16)ar[i];
            mh[i] = h; mlo[i] = (_Float16)((ar[i] - (float)h) * 1024.0f);
        }
        // next M + its f2/sm chain overlaps this step's MFMA chain
        float smn = sm;
        if (s + 1 < Ln) {
            t += ds;
            arow = *(const float4*)&Ml[t * 256 + ln * 16 + qd * 4];
            float f2n = arow.x*arow.x + arow.y*arow.y + arow.z*arow.z + arow.w*arow.w;
#pragma unroll
            for (int off = 1; off < 64; off <<= 1) f2n += __shfl_xor(f2n, off);
            smn = 4.0f * rsqrtf(f2n + 1e-12f);
        }
        // split running product (hi + lo*1024)
        f16x4 qh, ql;
#pragma unroll
        for (int r = 0; r < 4; ++r) {
            const _Float16 h = (_Float16)v[r];
            qh[r] = h; ql[r] = (_Float16)((v[r] - (float)h) * 1024.0f);
        }
        f32x4 a1 = {0.f,0.f,0.f,0.f}, a2 = {0.f,0.f,0.f,0.f};
        a1 = __builtin_amdgcn_mfma_f32_16x16x16f16(mh,  qh, a1, 0, 0, 0);
        a2 = __builtin_amdgcn_mfma_f32_16x16x16f16(mh,  ql, a2, 0, 0, 0);
        a2 = __builtin_amdgcn_mfma_f32_16x16x16f16(mlo, qh, a2, 0, 0, 0);
#pragma unroll
        for (int r = 0; r < 4; ++r) v[r] = a1[r] + a2[r] * (1.0f / 1024.0f);

        if (s & 1) {                          // rescale every 2nd step (value arbitrary)
            float mx = 0.f;
#pragma unroll
            for (int r = 0; r < 4; ++r) mx = fmaxf(mx, fabsf(v[r]));
#pragma unroll
            for (int off = 1; off < 64; off <<= 1) mx = fmaxf(mx, __shfl_xor(mx, off));
            const float inv = 1.0f / (mx + 1e-30f);
#pragma unroll
            for (int r = 0; r < 4; ++r) v[r] *= inv;
        }
        // store prefix over this chunk's slot tcur (f16; stageC2 normalizes -> scale free)
        _Float16* Pp = (_Float16*)((char*)mp + (size_t)tcur * 1024 + dir * 512);
#pragma unroll
        for (int r = 0; r < 4; ++r)
            Pp[(qd * 4 + r) * 16 + ln] = (_Float16)v[r];
        sm = smn;
    }

    // final L2 normalize + store chunk map for stageB (row-major)
    float ss = 0.f;
#pragma unroll
    for (int r = 0; r < 4; ++r) ss += v[r] * v[r];
#pragma unroll
    for (int off = 1; off < 64; off <<= 1) ss += __shfl_xor(ss, off);
    const float sl = 1.0f / (sqrtf(ss) + 1e-30f);
    float* qo = q + ((size_t)(dir * SS + seq) * Cn + c) * 256;
#pragma unroll
    for (int r = 0; r < 4; ++r)
        qo[(qd * 4 + r) * 16 + ln] = v[r] * sl;
}

// ---------------- Stage B: cross-chunk vector propagation (r3-proven) ---------------------
__global__ __launch_bounds__(64) void stageB_kernel(const float* __restrict__ q,
                                                    float* __restrict__ vs, int SS)
{
    const int lane = threadIdx.x & 63;
    const int i = lane & 15;
    const int chain = blockIdx.x;
    const int dir = (chain >= SS) ? 1 : 0;
    const int seq = chain - dir * SS;
    const float* qb = q + (size_t)(dir * SS + seq) * Cn * 256;
    float* vb = vs + (size_t)(dir * SS + seq) * Cn * 16;

    float myw = (i == 0) ? 1.0f : 0.0f;
    float wv[16];
#pragma unroll
    for (int k2 = 0; k2 < 16; ++k2) wv[k2] = (k2 == 0) ? 1.0f : 0.0f;

    int cc = dir ? (Cn - 1) : 0;
    const float* Qp = qb + (size_t)cc * 256 + i * 16;
    float4 q0 = *(const float4*)(Qp + 0);
    float4 q1 = *(const float4*)(Qp + 4);
    float4 q2 = *(const float4*)(Qp + 8);
    float4 q3 = *(const float4*)(Qp + 12);

    for (int s = 0; s < Cn; ++s) {
        vb[cc * 16 + i] = myw;
        float nv = q0.x*wv[0] + q0.y*wv[1] + q0.z*wv[2] + q0.w*wv[3]
                 + q1.x*wv[4] + q1.y*wv[5] + q1.z*wv[6] + q1.w*wv[7]
                 + q2.x*wv[8] + q2.y*wv[9] + q2.z*wv[10] + q2.w*wv[11]
                 + q3.x*wv[12] + q3.y*wv[13] + q3.z*wv[14] + q3.w*wv[15];
        if (s + 1 < Cn) {                       // prefetch next chunk's Q
            const int ccn = dir ? (Cn - 2 - s) : (s + 1);
            const float* Qn = qb + (size_t)ccn * 256 + i * 16;
            q0 = *(const float4*)(Qn + 0);
            q1 = *(const float4*)(Qn + 4);
            q2 = *(const float4*)(Qn + 8);
            q3 = *(const float4*)(Qn + 12);
        }
        float s2 = nv * nv;
        s2 += __shfl_xor(s2, 1); s2 += __shfl_xor(s2, 2);
        s2 += __shfl_xor(s2, 4); s2 += __shfl_xor(s2, 8);
        const float wn = nv / (sqrtf(s2) + 1e-20f);
        myw = wn;
#pragma unroll
        for (int k2 = 0; k2 < 16; ++k2) wv[k2] = __shfl(wn, (lane & 48) | k2);
        cc = dir ? (Cn - 2 - s) : (s + 1);
    }
}

// ---------------- Stage C2: parallel replay x_t = normalize(P_t . v_start) ----------------
// P aliased in m: slot t holds dir0 prefix at +0 B, dir1 prefix at +512 B. One wave per
// (dir,seq,c); 8 independent t-groups of 4 slots each (full ILP, coalesced f16 reads).
__global__ __launch_bounds__(256) void stageC2_kernel(const float* __restrict__ m,
                                                      const float* __restrict__ vs,
                                                      _Float16* __restrict__ x, int SS)
{
    const int tid = threadIdx.x;
    const int wave = tid >> 6, lane = tid & 63;
    const int dsc = blockIdx.x * 4 + wave;        // (dir*SS + seq)*Cn + c
    const int dirseq = dsc >> 6, c = dsc & (Cn - 1);
    const int dir = (dirseq >= SS) ? 1 : 0;
    const int seq = dirseq - dir * SS;
    const int bbl = seq >> 4, h = seq & 15;
    const _Float16* Pp = (const _Float16*)((const char*)m
                       + ((size_t)seq * Tdim + c * Ln) * 1024 + dir * 512);
    const float* vp = vs + (size_t)dsc * 16;

    float v[16];
#pragma unroll
    for (int k = 0; k < 16; ++k) v[k] = vp[k];    // wave-uniform -> broadcast loads

    const int tt = lane >> 4, j = lane & 15;
    const int t0 = c * Ln;
#pragma unroll
    for (int g = 0; g < 8; ++g) {
        const int s = g * 4 + tt;
        const _Float16* pr = Pp + (size_t)s * 512 + j * 16;   // slot stride 1024 B = 512 f16
        const f16x8 p0 = *(const f16x8*)(pr);
        const f16x8 p1 = *(const f16x8*)(pr + 8);
        float nv = 0.f;
#pragma unroll
        for (int k = 0; k < 8; ++k) nv += (float)p0[k] * v[k];
#pragma unroll
        for (int k = 0; k < 8; ++k) nv += (float)p1[k] * v[k + 8];
        float s2 = nv * nv;
        s2 += __shfl_xor(s2, 1); s2 += __shfl_xor(s2, 2);
        s2 += __shfl_xor(s2, 4); s2 += __shfl_xor(s2, 8);
        const float vn = nv / (sqrtf(s2) + 1e-6f);   // reference VEC_EPS semantics
        const int t = t0 + s;                        // slot t holds prefix for output t (both dirs)
        x[(((size_t)bbl * Tdim + t) * NHd + h) * 32 + dir * 16 + j] = (_Float16)vn;
    }
}

// ---------------- GEMM2 (f16 MFMA): out = gelu(x @ W_out + b_out) -------------------------
__global__ __launch_bounds__(256) void gemm2_f16(const _Float16* __restrict__ A,
                                                 const _Float16* __restrict__ BT,
                                                 const float* __restrict__ bias,
                                                 float* __restrict__ out, int row0)
{
    __shared__ _Float16 Al[128 * LSTR];
    __shared__ _Float16 Bl[128 * LSTR];
    const int tid = threadIdx.x;
    const int wave = tid >> 6, lane = tid & 63;
    const int wm = wave & 1, wn = wave >> 1;
    const int qd = lane >> 4, ln = lane & 15;
    const int r0 = blockIdx.y * 128;
    const int c0 = blockIdx.x * 128;

    f32x4 acc[4][4] = {{{0.f,0.f,0.f,0.f}}};

    const int sr = tid >> 2, sc = tid & 3;
    const _Float16* Ag = A  + (size_t)(r0 + sr) * 512 + sc * 8;
    const _Float16* Bg = BT + (size_t)(c0 + sr) * 512 + sc * 8;
    _Float16* Alw = &Al[sr * LSTR + sc * 8];
    _Float16* Blw = &Bl[sr * LSTR + sc * 8];

    for (int k0 = 0; k0 < 512; k0 += 32) {
        const f16x8 a0 = *(const f16x8*)(Ag + k0);
        const f16x8 a1 = *(const f16x8*)(Ag + (size_t)64 * 512 + k0);
        const f16x8 b0 = *(const f16x8*)(Bg + k0);
        const f16x8 b1 = *(const f16x8*)(Bg + (size_t)64 * 512 + k0);
        __syncthreads();
        *(f16x8*)(Alw)             = a0;
        *(f16x8*)(Alw + 64 * LSTR) = a1;
        *(f16x8*)(Blw)             = b0;
        *(f16x8*)(Blw + 64 * LSTR) = b1;
        __syncthreads();
        f16x8 af[4], bfr[4];
#pragma unroll
        for (int mt = 0; mt < 4; ++mt)
            af[mt] = *(const f16x8*)&Al[(wm * 64 + mt * 16 + ln) * LSTR + qd * 8];
#pragma unroll
        for (int nt = 0; nt < 4; ++nt)
            bfr[nt] = *(const f16x8*)&Bl[(wn * 64 + nt * 16 + ln) * LSTR + qd * 8];
#pragma unroll
        for (int mt = 0; mt < 4; ++mt)
#pragma unroll
            for (int nt = 0; nt < 4; ++nt)
                acc[mt][nt] = __builtin_amdgcn_mfma_f32_16x16x32_f16(af[mt], bfr[nt], acc[mt][nt], 0, 0, 0);
    }
#pragma unroll
    for (int nt = 0; nt < 4; ++nt) {
        const int c = c0 + wn * 64 + nt * 16 + ln;
        const float bv = bias[c];
#pragma unroll
        for (int mt = 0; mt < 4; ++mt) {
#pragma unroll
            for (int r = 0; r < 4; ++r) {
                const int row = r0 + wm * 64 + mt * 16 + qd * 4 + r;
                float v = acc[mt][nt][r] + bv;
                v = 0.5f * v * (1.0f + erff(v * 0.70710678118654752f));
                out[(size_t)(row0 + row) * 1024 + c] = v;
            }
        }
    }
}

extern "C" void kernel_launch(void* const* d_in, const int* in_sizes, int n_in,
                              void* d_out, int out_size, void* d_ws, size_t ws_size,
                              hipStream_t stream)
{
    const float* hs    = (const float*)d_in[0];
    const float* W_mat = (const float*)d_in[1];
    const float* b_mat = (const float*)d_in[2];
    const float* W_out = (const float*)d_in[3];
    const float* b_out = (const float*)d_in[4];
    float* out = (float*)d_out;

    // layout: W2T(1M) Bcat(24M) | per bb-group: m 32M (P f16 aliased over it) |
    //         qx 2M (q f32 / x f16 aliased) | Acat 12M | vs 128K
    const size_t per_bb = (32ull << 20) + (2ull << 20) + (12ull << 20) + (128ull << 10);
    const size_t wbase  = 25ull << 20;
    int nbb = 8;
    while (nbb > 1 && ws_size < wbase + (size_t)nbb * per_bb) nbb >>= 1;

    char* base = (char*)d_ws;
    _Float16* W2T = (_Float16*)base;
    _Float16* Bc  = (_Float16*)(base + (1ull << 20));
    size_t off = wbase;
    float* m  = (float*)(base + off);  off += (size_t)nbb * (32ull << 20);
    float* qx = (float*)(base + off);  off += (size_t)nbb * (2ull << 20);
    _Float16* Ac = (_Float16*)(base + off); off += (size_t)nbb * (12ull << 20);
    float* vs = (float*)(base + off);

    conv_B_kernel<<<dim3(128, 32), 256, 0, stream>>>(W_mat, Bc);
    conv_W2T_kernel<<<dim3(32, 16), 256, 0, stream>>>(W_out, W2T);

    for (int bb0 = 0; bb0 < 8; bb0 += nbb) {
        const int row0 = bb0 * Tdim;
        const int SS = nbb * 16;
        conv_A_kernel<<<nbb * 1024, 256, 0, stream>>>(hs + (size_t)row0 * HIDd, Ac);
        gemm1_8ph<<<dim3(16, nbb * 8), 512, 0, stream>>>(Ac, Bc, b_mat, m);
        stageA2_mfma<<<SS * Cn, 128, 0, stream>>>(m, qx, SS);
        stageB_kernel<<<2 * SS, 64, 0, stream>>>(qx, vs, SS);
        stageC2_kernel<<<SS * Cn / 2, 256, 0, stream>>>(m, vs, (_Float16*)qx, SS);
        gemm2_f16<<<dim3(8, nbb * 16), 256, 0, stream>>>((_Float16*)qx, W2T, b_out, out, row0);
    }
}

// Round 6
// 786.333 us; speedup vs baseline: 1.1974x; 1.1165x over previous
//
#include <hip/hip_runtime.h>
#include <math.h>

#define Tdim 2048
#define HIDd 1024
#define NHd 16
#define NCOL 4096         // NH*16*16
#define Cn 64             // chunks per sequence
#define Ln 32             // chunk length (Cn*Ln == Tdim)
#define LSTR 40           // f16 elems per LDS row (80 B): bank-friendly pad (gemm2)
#define KCAT 3072         // concatenated K: [Ah|Ah/32|Al*32] x [Bh|Bl*32|Bh/32]
#define KB 6144           // KCAT * sizeof(_Float16)

typedef _Float16 f16x4  __attribute__((ext_vector_type(4)));
typedef _Float16 f16x8  __attribute__((ext_vector_type(8)));
typedef float    f32x4  __attribute__((ext_vector_type(4)));

typedef __attribute__((address_space(1))) void gvoid_t;
typedef __attribute__((address_space(3))) void lvoid_t;

// ---------------- hs (rows x 1024 fp32) -> A_cat (rows x 3072 f16) ------------------------
__global__ __launch_bounds__(256) void conv_A_kernel(const float* __restrict__ hs,
                                                     _Float16* __restrict__ Ac)
{
    const size_t i = ((size_t)blockIdx.x * 256 + threadIdx.x) * 8;
    const size_t r = i >> 10, k = i & 1023;
    const float4 x0 = *(const float4*)(hs + i);
    const float4 x1 = *(const float4*)(hs + i + 4);
    const float v[8] = {x0.x, x0.y, x0.z, x0.w, x1.x, x1.y, x1.z, x1.w};
    f16x8 h, hm, l;
#pragma unroll
    for (int j = 0; j < 8; ++j) {
        const _Float16 hh = (_Float16)v[j];
        h[j]  = hh;
        hm[j] = (_Float16)(v[j] * 0.03125f);          // == hh/32 exactly (pow2 scale)
        l[j]  = (_Float16)((v[j] - (float)hh) * 32.0f);
    }
    _Float16* o = Ac + r * KCAT + k;
    *(f16x8*)(o)        = h;
    *(f16x8*)(o + 1024) = hm;
    *(f16x8*)(o + 2048) = l;
}

// ---------------- W_mat (1024 x 4096 fp32) -> B_cat (4096 x 3072 f16) ---------------------
__global__ __launch_bounds__(256) void conv_B_kernel(const float* __restrict__ W,
                                                     _Float16* __restrict__ Bc)
{
    __shared__ float t[32][33];
    const int tx = threadIdx.x & 31, ty = threadIdx.x >> 5;   // ty 0..7
    const int n0 = blockIdx.x * 32, k0 = blockIdx.y * 32;
#pragma unroll
    for (int i = 0; i < 4; ++i)
        t[ty + i * 8][tx] = W[(size_t)(k0 + ty + i * 8) * NCOL + n0 + tx];
    __syncthreads();
#pragma unroll
    for (int i = 0; i < 4; ++i) {
        const float w = t[tx][ty + i * 8];
        const _Float16 h = (_Float16)w;
        const size_t o = (size_t)(n0 + ty + i * 8) * KCAT + k0 + tx;
        Bc[o]        = h;
        Bc[o + 1024] = (_Float16)((w - (float)h) * 32.0f);
        Bc[o + 2048] = (_Float16)((float)h * 0.03125f);   // exact
    }
}

// ---------------- W_out (512 x 1024 fp32) -> W2T (1024 x 512 fp16) ------------------------
__global__ __launch_bounds__(256) void conv_W2T_kernel(const float* __restrict__ W,
                                                       _Float16* __restrict__ WT)
{
    __shared__ float t[32][33];
    const int tx = threadIdx.x & 31, ty = threadIdx.x >> 5;
    const int n0 = blockIdx.x * 32, k0 = blockIdx.y * 32;
#pragma unroll
    for (int i = 0; i < 4; ++i)
        t[ty + i * 8][tx] = W[(size_t)(k0 + ty + i * 8) * 1024 + n0 + tx];
    __syncthreads();
#pragma unroll
    for (int i = 0; i < 4; ++i)
        WT[(size_t)(n0 + ty + i * 8) * 512 + k0 + tx] = (_Float16)t[tx][ty + i * 8];
}

// ---------------- GEMM1 + fused stage A: 256x256 tile, 8-phase pipeline -------------------
// After the K-loop, the dead 128 KB staging LDS is reused as a 128x256 f32 half-tile of
// M(+bias). Two phases: waves wm==half dump acc -> barrier -> 8 waves run 8 chunk-chains
// (4 chunks x 2 dirs; arithmetic identical to the r5 stageA2 which passed). Chains write
// f16 prefixes over the m buffer (slot t: dir0 bytes 0-511, dir1 512-1023) + q chunk maps.
#define MFMA_PHASE(CPH) \
    _Pragma("unroll") \
    for (int m2_ = 0; m2_ < 2; ++m2_) { \
        _Pragma("unroll") \
        for (int nt_ = 0; nt_ < 4; ++nt_) { \
            acc[(CPH)*2 + m2_][nt_] = __builtin_amdgcn_mfma_f32_16x16x32_f16(af[m2_][0], bf[nt_][0], acc[(CPH)*2 + m2_][nt_], 0, 0, 0); \
            acc[(CPH)*2 + m2_][nt_] = __builtin_amdgcn_mfma_f32_16x16x32_f16(af[m2_][1], bf[nt_][1], acc[(CPH)*2 + m2_][nt_], 0, 0, 0); \
        } \
    }

#define PHASE(BUF, CPH, STAGE_EXPR, DOGATE) do { \
    af[0][0] = readA(BUF, (CPH)*2,     0); \
    af[0][1] = readA(BUF, (CPH)*2,     1); \
    af[1][0] = readA(BUF, (CPH)*2 + 1, 0); \
    af[1][1] = readA(BUF, (CPH)*2 + 1, 1); \
    if ((CPH) == 0) { \
        _Pragma("unroll") \
        for (int nt_ = 0; nt_ < 4; ++nt_) { bf[nt_][0] = readB(BUF, nt_, 0); bf[nt_][1] = readB(BUF, nt_, 1); } \
    } \
    STAGE_EXPR; \
    asm volatile("s_barrier" ::: "memory"); \
    asm volatile("s_waitcnt lgkmcnt(0)" ::: "memory"); \
    __builtin_amdgcn_sched_barrier(0); \
    __builtin_amdgcn_s_setprio(1); \
    MFMA_PHASE(CPH) \
    __builtin_amdgcn_s_setprio(0); \
    if (DOGATE) { \
        if (notlast) asm volatile("s_waitcnt vmcnt(6)" ::: "memory"); \
        else         asm volatile("s_waitcnt vmcnt(0)" ::: "memory"); \
    } \
    asm volatile("s_barrier" ::: "memory"); \
} while (0)

__global__ __launch_bounds__(512, 2) void gemm1_8ph(const _Float16* __restrict__ A,
                                                    const _Float16* __restrict__ B,
                                                    const float* __restrict__ bias,
                                                    float* __restrict__ Mout,
                                                    float* __restrict__ qout, int SS)
{
    __shared__ __align__(16) _Float16 sAB[4][256 * 64];   // [0..1]=A dbuf, [2..3]=B dbuf
    const int tid = threadIdx.x;
    const int lane = tid & 63;
    const int wid = tid >> 6;
    const int wm = wid >> 2, wn = wid & 3;        // wave grid 2 (M) x 4 (N)
    const int q = lane >> 4, ln = lane & 15;
    const int col0 = blockIdx.x * 256;
    const int row0 = blockIdx.y * 256;

    const char* Ab = (const char*)A + (size_t)row0 * KB;
    const char* Bb = (const char*)B + (size_t)col0 * KB;

    auto stage_chunk = [&](const char* g, int fr, int kt, char* ldsbase) {
        const int rr = tid >> 3;
        const int cb = (tid & 7) << 4;
        const char* src = g + (size_t)(fr + rr) * KB + (size_t)kt * 128 + (cb ^ ((rr & 7) << 4));
        char* dst = ldsbase + ((tid >> 6) << 10);
        __builtin_amdgcn_global_load_lds((gvoid_t*)src, (lvoid_t*)dst, 16, 0, 0);
    };
    auto stageA2g = [&](int b, int t, int h) {
        stage_chunk(Ab, h * 64,       t, (char*)&sAB[b][0] + (size_t)(h * 64) * 128);
        stage_chunk(Ab, 128 + h * 64, t, (char*)&sAB[b][0] + (size_t)(128 + h * 64) * 128);
    };
    auto stageB2 = [&](int b, int t, int h) {
        stage_chunk(Bb, h * 128,      t, (char*)&sAB[2 + b][0] + (size_t)(h * 128) * 128);
        stage_chunk(Bb, h * 128 + 64, t, (char*)&sAB[2 + b][0] + (size_t)(h * 128 + 64) * 128);
    };
    auto readA = [&](int b, int mf, int ks) -> f16x8 {
        const int r = wm * 128 + mf * 16 + ln;
        return *(const f16x8*)((const char*)&sAB[b][0] + r * 128 + ((ks * 64 + q * 16) ^ ((r & 7) << 4)));
    };
    auto readB = [&](int b, int nt, int ks) -> f16x8 {
        const int r = wn * 64 + nt * 16 + ln;
        return *(const f16x8*)((const char*)&sAB[2 + b][0] + r * 128 + ((ks * 64 + q * 16) ^ ((r & 7) << 4)));
    };

    stageB2(0, 0, 0); stageB2(0, 0, 1); stageA2g(0, 0, 0); stageA2g(0, 0, 1);
    stageB2(1, 1, 0); stageB2(1, 1, 1); stageA2g(1, 1, 0);

    f32x4 acc[8][4];
    const f32x4 z4 = {0.f, 0.f, 0.f, 0.f};
#pragma unroll
    for (int mf = 0; mf < 8; ++mf)
#pragma unroll
        for (int nt = 0; nt < 4; ++nt) acc[mf][nt] = z4;

    asm volatile("s_waitcnt vmcnt(6)" ::: "memory");
    asm volatile("s_barrier" ::: "memory");

    f16x8 af[2][2];
    f16x8 bf[4][2];

#pragma unroll 1
    for (int it = 0; it < 24; ++it) {
        const int t0 = it * 2;
        const bool notlast = (it != 23);
        PHASE(0, 0, (stageA2g(1, t0 + 1, 1)), 0);
        PHASE(0, 1, (notlast ? stageB2(0, t0 + 2, 0) : (void)0), 0);
        PHASE(0, 2, (notlast ? stageB2(0, t0 + 2, 1) : (void)0), 0);
        PHASE(0, 3, (notlast ? stageA2g(0, t0 + 2, 0) : (void)0), 1);
        PHASE(1, 0, (notlast ? stageA2g(0, t0 + 2, 1) : (void)0), 0);
        PHASE(1, 1, (notlast ? stageB2(1, t0 + 3, 0) : (void)0), 0);
        PHASE(1, 2, (notlast ? stageB2(1, t0 + 3, 1) : (void)0), 0);
        PHASE(1, 3, (notlast ? stageA2g(1, t0 + 3, 0) : (void)0), 1);
    }

    // ---------------- fused stage A epilogue ----------------
    float* Mf = (float*)&sAB[0][0];               // 128 x 256 f32 half-tile (128 KB)
    const int seq = ((row0 >> 11) << 4) + blockIdx.x;   // bbl*16 + head
    const int cc   = wid & 3;                     // chunk-in-half
    const int dirw = wid >> 2;                    // 0 = lr, 1 = rl
    float bv[4];
#pragma unroll
    for (int nt = 0; nt < 4; ++nt) bv[nt] = bias[col0 + wn * 64 + nt * 16 + ln];

#pragma unroll 1
    for (int half = 0; half < 2; ++half) {
        __syncthreads();                          // LDS free / prev-phase readers done
        if (wm == half) {
#pragma unroll
            for (int mf = 0; mf < 8; ++mf)
#pragma unroll
                for (int nt = 0; nt < 4; ++nt)
#pragma unroll
                    for (int r = 0; r < 4; ++r)
                        Mf[(mf * 16 + q * 4 + r) * 256 + wn * 64 + nt * 16 + ln]
                            = acc[mf][nt][r] + bv[nt];
        }
        __syncthreads();

        const int cblk = half * 4 + cc;           // chunk 0..7 within block
        const int tb   = cblk * 32 - half * 128;  // local row base in Mf
        float v[4];
#pragma unroll
        for (int r = 0; r < 4; ++r) v[r] = (q * 4 + r == ln) ? 1.0f : 0.0f;

        int tl = dirw ? (tb + 31) : tb;
        const int ds = dirw ? -1 : 1;
        float4 arow = *(const float4*)&Mf[tl * 256 + ln * 16 + q * 4];
        float f2 = arow.x*arow.x + arow.y*arow.y + arow.z*arow.z + arow.w*arow.w;
#pragma unroll
        for (int off = 1; off < 64; off <<= 1) f2 += __shfl_xor(f2, off);
        float sm = 4.0f * rsqrtf(f2 + 1e-12f);

        for (int s = 0; s < Ln; ++s) {
            const int tabs = (row0 & 2047) + (dirw ? (cblk * 32 + 31 - s) : (cblk * 32 + s));
            // split sm-scaled M row fragment (hi + lo*1024)
            f16x4 mh, mlo;
            const float ar[4] = {arow.x * sm, arow.y * sm, arow.z * sm, arow.w * sm};
#pragma unroll
            for (int i = 0; i < 4; ++i) {
                const _Float16 h = (_Float16)ar[i];
                mh[i] = h; mlo[i] = (_Float16)((ar[i] - (float)h) * 1024.0f);
            }
            // next M row + its f2/sm chain overlaps this step's MFMA chain
            float smn = sm;
            if (s + 1 < Ln) {
                tl += ds;
                arow = *(const float4*)&Mf[tl * 256 + ln * 16 + q * 4];
                float f2n = arow.x*arow.x + arow.y*arow.y + arow.z*arow.z + arow.w*arow.w;
#pragma unroll
                for (int off = 1; off < 64; off <<= 1) f2n += __shfl_xor(f2n, off);
                smn = 4.0f * rsqrtf(f2n + 1e-12f);
            }
            // split running product (hi + lo*1024)
            f16x4 qh, ql;
#pragma unroll
            for (int r = 0; r < 4; ++r) {
                const _Float16 h = (_Float16)v[r];
                qh[r] = h; ql[r] = (_Float16)((v[r] - (float)h) * 1024.0f);
            }
            f32x4 a1 = {0.f,0.f,0.f,0.f}, a2 = {0.f,0.f,0.f,0.f};
            a1 = __builtin_amdgcn_mfma_f32_16x16x16f16(mh,  qh, a1, 0, 0, 0);
            a2 = __builtin_amdgcn_mfma_f32_16x16x16f16(mh,  ql, a2, 0, 0, 0);
            a2 = __builtin_amdgcn_mfma_f32_16x16x16f16(mlo, qh, a2, 0, 0, 0);
#pragma unroll
            for (int r = 0; r < 4; ++r) v[r] = a1[r] + a2[r] * (1.0f / 1024.0f);

            if (s & 1) {                          // rescale every 2nd step (value arbitrary)
                float mx = 0.f;
#pragma unroll
                for (int r = 0; r < 4; ++r) mx = fmaxf(mx, fabsf(v[r]));
#pragma unroll
                for (int off = 1; off < 64; off <<= 1) mx = fmaxf(mx, __shfl_xor(mx, off));
                const float inv = 1.0f / (mx + 1e-30f);
#pragma unroll
                for (int r = 0; r < 4; ++r) v[r] *= inv;
            }
            // prefix store (f16) over m slot tabs (stageC2 normalizes -> scale free)
            _Float16* Pp = (_Float16*)((char*)Mout
                         + ((size_t)seq * Tdim + tabs) * 1024 + dirw * 512);
#pragma unroll
            for (int r = 0; r < 4; ++r)
                Pp[(q * 4 + r) * 16 + ln] = (_Float16)v[r];
            sm = smn;
        }

        // final L2 normalize + chunk map for stageB
        float ss = 0.f;
#pragma unroll
        for (int r = 0; r < 4; ++r) ss += v[r] * v[r];
#pragma unroll
        for (int off = 1; off < 64; off <<= 1) ss += __shfl_xor(ss, off);
        const float sl = 1.0f / (sqrtf(ss) + 1e-30f);
        const int cabs = ((row0 & 2047) >> 5) + cblk;
        float* qo = qout + ((size_t)(dirw * SS + seq) * Cn + cabs) * 256;
#pragma unroll
        for (int r = 0; r < 4; ++r)
            qo[(q * 4 + r) * 16 + ln] = v[r] * sl;
    }
}

// ---------------- Stage B: cross-chunk vector propagation (r3-proven) ---------------------
__global__ __launch_bounds__(64) void stageB_kernel(const float* __restrict__ q,
                                                    float* __restrict__ vs, int SS)
{
    const int lane = threadIdx.x & 63;
    const int i = lane & 15;
    const int chain = blockIdx.x;
    const int dir = (chain >= SS) ? 1 : 0;
    const int seq = chain - dir * SS;
    const float* qb = q + (size_t)(dir * SS + seq) * Cn * 256;
    float* vb = vs + (size_t)(dir * SS + seq) * Cn * 16;

    float myw = (i == 0) ? 1.0f : 0.0f;
    float wv[16];
#pragma unroll
    for (int k2 = 0; k2 < 16; ++k2) wv[k2] = (k2 == 0) ? 1.0f : 0.0f;

    int cc = dir ? (Cn - 1) : 0;
    const float* Qp = qb + (size_t)cc * 256 + i * 16;
    float4 q0 = *(const float4*)(Qp + 0);
    float4 q1 = *(const float4*)(Qp + 4);
    float4 q2 = *(const float4*)(Qp + 8);
    float4 q3 = *(const float4*)(Qp + 12);

    for (int s = 0; s < Cn; ++s) {
        vb[cc * 16 + i] = myw;
        float nv = q0.x*wv[0] + q0.y*wv[1] + q0.z*wv[2] + q0.w*wv[3]
                 + q1.x*wv[4] + q1.y*wv[5] + q1.z*wv[6] + q1.w*wv[7]
                 + q2.x*wv[8] + q2.y*wv[9] + q2.z*wv[10] + q2.w*wv[11]
                 + q3.x*wv[12] + q3.y*wv[13] + q3.z*wv[14] + q3.w*wv[15];
        if (s + 1 < Cn) {                       // prefetch next chunk's Q
            const int ccn = dir ? (Cn - 2 - s) : (s + 1);
            const float* Qn = qb + (size_t)ccn * 256 + i * 16;
            q0 = *(const float4*)(Qn + 0);
            q1 = *(const float4*)(Qn + 4);
            q2 = *(const float4*)(Qn + 8);
            q3 = *(const float4*)(Qn + 12);
        }
        float s2 = nv * nv;
        s2 += __shfl_xor(s2, 1); s2 += __shfl_xor(s2, 2);
        s2 += __shfl_xor(s2, 4); s2 += __shfl_xor(s2, 8);
        const float wn = nv / (sqrtf(s2) + 1e-20f);
        myw = wn;
#pragma unroll
        for (int k2 = 0; k2 < 16; ++k2) wv[k2] = __shfl(wn, (lane & 48) | k2);
        cc = dir ? (Cn - 2 - s) : (s + 1);
    }
}

// ---------------- Stage C2: parallel replay x_t = normalize(P_t . v_start) ----------------
// P aliased in m: slot t holds dir0 prefix at +0 B, dir1 prefix at +512 B. One wave per
// (dir,seq,c); 8 independent t-groups of 4 slots each (full ILP, coalesced f16 reads).
__global__ __launch_bounds__(256) void stageC2_kernel(const float* __restrict__ m,
                                                      const float* __restrict__ vs,
                                                      _Float16* __restrict__ x, int SS)
{
    const int tid = threadIdx.x;
    const int wave = tid >> 6, lane = tid & 63;
    const int dsc = blockIdx.x * 4 + wave;        // (dir*SS + seq)*Cn + c
    const int dirseq = dsc >> 6, c = dsc & (Cn - 1);
    const int dir = (dirseq >= SS) ? 1 : 0;
    const int seq = dirseq - dir * SS;
    const int bbl = seq >> 4, h = seq & 15;
    const _Float16* Pp = (const _Float16*)((const char*)m
                       + ((size_t)seq * Tdim + c * Ln) * 1024 + dir * 512);
    const float* vp = vs + (size_t)dsc * 16;

    float v[16];
#pragma unroll
    for (int k = 0; k < 16; ++k) v[k] = vp[k];    // wave-uniform -> broadcast loads

    const int tt = lane >> 4, j = lane & 15;
    const int t0 = c * Ln;
#pragma unroll
    for (int g = 0; g < 8; ++g) {
        const int s = g * 4 + tt;
        const _Float16* pr = Pp + (size_t)s * 512 + j * 16;   // slot stride 1024 B = 512 f16
        const f16x8 p0 = *(const f16x8*)(pr);
        const f16x8 p1 = *(const f16x8*)(pr + 8);
        float nv = 0.f;
#pragma unroll
        for (int k = 0; k < 8; ++k) nv += (float)p0[k] * v[k];
#pragma unroll
        for (int k = 0; k < 8; ++k) nv += (float)p1[k] * v[k + 8];
        float s2 = nv * nv;
        s2 += __shfl_xor(s2, 1); s2 += __shfl_xor(s2, 2);
        s2 += __shfl_xor(s2, 4); s2 += __shfl_xor(s2, 8);
        const float vn = nv / (sqrtf(s2) + 1e-6f);   // reference VEC_EPS semantics
        const int t = t0 + s;                        // slot t holds prefix for output t (both dirs)
        x[(((size_t)bbl * Tdim + t) * NHd + h) * 32 + dir * 16 + j] = (_Float16)vn;
    }
}

// ---------------- GEMM2 (f16 MFMA): out = gelu(x @ W_out + b_out) -------------------------
__global__ __launch_bounds__(256) void gemm2_f16(const _Float16* __restrict__ A,
                                                 const _Float16* __restrict__ BT,
                                                 const float* __restrict__ bias,
                                                 float* __restrict__ out, int row0)
{
    __shared__ _Float16 Al[128 * LSTR];
    __shared__ _Float16 Bl[128 * LSTR];
    const int tid = threadIdx.x;
    const int wave = tid >> 6, lane = tid & 63;
    const int wm = wave & 1, wn = wave >> 1;
    const int qd = lane >> 4, ln = lane & 15;
    const int r0 = blockIdx.y * 128;
    const int c0 = blockIdx.x * 128;

    f32x4 acc[4][4] = {{{0.f,0.f,0.f,0.f}}};

    const int sr = tid >> 2, sc = tid & 3;
    const _Float16* Ag = A  + (size_t)(r0 + sr) * 512 + sc * 8;
    const _Float16* Bg = BT + (size_t)(c0 + sr) * 512 + sc * 8;
    _Float16* Alw = &Al[sr * LSTR + sc * 8];
    _Float16* Blw = &Bl[sr * LSTR + sc * 8];

    for (int k0 = 0; k0 < 512; k0 += 32) {
        const f16x8 a0 = *(const f16x8*)(Ag + k0);
        const f16x8 a1 = *(const f16x8*)(Ag + (size_t)64 * 512 + k0);
        const f16x8 b0 = *(const f16x8*)(Bg + k0);
        const f16x8 b1 = *(const f16x8*)(Bg + (size_t)64 * 512 + k0);
        __syncthreads();
        *(f16x8*)(Alw)             = a0;
        *(f16x8*)(Alw + 64 * LSTR) = a1;
        *(f16x8*)(Blw)             = b0;
        *(f16x8*)(Blw + 64 * LSTR) = b1;
        __syncthreads();
        f16x8 af[4], bfr[4];
#pragma unroll
        for (int mt = 0; mt < 4; ++mt)
            af[mt] = *(const f16x8*)&Al[(wm * 64 + mt * 16 + ln) * LSTR + qd * 8];
#pragma unroll
        for (int nt = 0; nt < 4; ++nt)
            bfr[nt] = *(const f16x8*)&Bl[(wn * 64 + nt * 16 + ln) * LSTR + qd * 8];
#pragma unroll
        for (int mt = 0; mt < 4; ++mt)
#pragma unroll
            for (int nt = 0; nt < 4; ++nt)
                acc[mt][nt] = __builtin_amdgcn_mfma_f32_16x16x32_f16(af[mt], bfr[nt], acc[mt][nt], 0, 0, 0);
    }
#pragma unroll
    for (int nt = 0; nt < 4; ++nt) {
        const int c = c0 + wn * 64 + nt * 16 + ln;
        const float bv = bias[c];
#pragma unroll
        for (int mt = 0; mt < 4; ++mt) {
#pragma unroll
            for (int r = 0; r < 4; ++r) {
                const int row = r0 + wm * 64 + mt * 16 + qd * 4 + r;
                float v = acc[mt][nt][r] + bv;
                v = 0.5f * v * (1.0f + erff(v * 0.70710678118654752f));
                out[(size_t)(row0 + row) * 1024 + c] = v;
            }
        }
    }
}

extern "C" void kernel_launch(void* const* d_in, const int* in_sizes, int n_in,
                              void* d_out, int out_size, void* d_ws, size_t ws_size,
                              hipStream_t stream)
{
    const float* hs    = (const float*)d_in[0];
    const float* W_mat = (const float*)d_in[1];
    const float* b_mat = (const float*)d_in[2];
    const float* W_out = (const float*)d_in[3];
    const float* b_out = (const float*)d_in[4];
    float* out = (float*)d_out;

    // layout: W2T(1M) Bcat(24M) | per bb-group: m 32M (f16 prefixes, written by gemm1) |
    //         qx 2M (q f32 / x f16 aliased) | Acat 12M | vs 128K
    const size_t per_bb = (32ull << 20) + (2ull << 20) + (12ull << 20) + (128ull << 10);
    const size_t wbase  = 25ull << 20;
    int nbb = 8;
    while (nbb > 1 && ws_size < wbase + (size_t)nbb * per_bb) nbb >>= 1;

    char* base = (char*)d_ws;
    _Float16* W2T = (_Float16*)base;
    _Float16* Bc  = (_Float16*)(base + (1ull << 20));
    size_t off = wbase;
    float* m  = (float*)(base + off);  off += (size_t)nbb * (32ull << 20);
    float* qx = (float*)(base + off);  off += (size_t)nbb * (2ull << 20);
    _Float16* Ac = (_Float16*)(base + off); off += (size_t)nbb * (12ull << 20);
    float* vs = (float*)(base + off);

    conv_B_kernel<<<dim3(128, 32), 256, 0, stream>>>(W_mat, Bc);
    conv_W2T_kernel<<<dim3(32, 16), 256, 0, stream>>>(W_out, W2T);

    for (int bb0 = 0; bb0 < 8; bb0 += nbb) {
        const int row0 = bb0 * Tdim;
        const int SS = nbb * 16;
        conv_A_kernel<<<nbb * 1024, 256, 0, stream>>>(hs + (size_t)row0 * HIDd, Ac);
        gemm1_8ph<<<dim3(16, nbb * 8), 512, 0, stream>>>(Ac, Bc, b_mat, m, qx, SS);
        stageB_kernel<<<2 * SS, 64, 0, stream>>>(qx, vs, SS);
        stageC2_kernel<<<SS * Cn / 2, 256, 0, stream>>>(m, vs, (_Float16*)qx, SS);
        gemm2_f16<<<dim3(8, nbb * 16), 256, 0, stream>>>((_Float16*)qx, W2T, b_out, out, row0);
    }
}